// Round 1
// baseline (4528.902 us; speedup 1.0000x reference)
//
#include <hip/hip_runtime.h>

#define LSTM_T 2048
#define LSTM_H 64

__device__ __forceinline__ float rl(float v, int lane) {
    return __int_as_float(__builtin_amdgcn_readlane(__float_as_int(v), lane));
}

__device__ __forceinline__ float fast_sigmoid(float x) {
    return 1.0f / (1.0f + __expf(-x));
}

__device__ __forceinline__ float fast_tanh(float x) {
    // tanh(x) = 1 - 2/(exp(2x)+1); saturates correctly at +-inf
    return 1.0f - 2.0f / (__expf(2.0f * x) + 1.0f);
}

__global__ __launch_bounds__(128) void lstm_cls_kernel(
    const float* __restrict__ x,      // [B, T, 1]
    const float* __restrict__ W_ih,   // [4H, 1]
    const float* __restrict__ W_hh,   // [4H, H]
    const float* __restrict__ b_ih,   // [4H]
    const float* __restrict__ b_hh,   // [4H]
    const float* __restrict__ W_lin,  // [3, H]
    const float* __restrict__ b_lin,  // [3]
    float* __restrict__ out)          // [B, 3]
{
    const int b    = blockIdx.x;
    const int tid  = threadIdx.x;
    const int lane = tid & 63;
    const int wv   = tid >> 6;   // 0: gates i,f   1: gates g,o

    __shared__ float sx[LSTM_T];
    __shared__ float ex[2][4][LSTM_H];   // double-buffered gate exchange

    // ---- stage this batch row of x into LDS (coalesced float4) ----
    {
        const float4* xr  = (const float4*)(x + (size_t)b * LSTM_T);
        float4*       sx4 = (float4*)sx;
        #pragma unroll
        for (int i = 0; i < LSTM_T / 4; i += 128) {
            sx4[i + tid] = xr[i + tid];
        }
    }

    const int rowA = wv * 128 + lane;        // gate block 0 (i) or 2 (g)
    const int rowB = wv * 128 + 64 + lane;   // gate block 1 (f) or 3 (o)

    // ---- recurrent weights: 2 rows per lane, resident in VGPRs ----
    float wA[LSTM_H], wB[LSTM_H];
    {
        const float4* pA = (const float4*)(W_hh + rowA * LSTM_H);
        const float4* pB = (const float4*)(W_hh + rowB * LSTM_H);
        #pragma unroll
        for (int q = 0; q < LSTM_H / 4; ++q) {
            float4 a  = pA[q];
            float4 bb = pB[q];
            wA[4*q+0] = a.x;  wA[4*q+1] = a.y;  wA[4*q+2] = a.z;  wA[4*q+3] = a.w;
            wB[4*q+0] = bb.x; wB[4*q+1] = bb.y; wB[4*q+2] = bb.z; wB[4*q+3] = bb.w;
        }
    }
    const float wihA  = W_ih[rowA];
    const float wihB  = W_ih[rowB];
    const float biasA = b_ih[rowA] + b_hh[rowA];
    const float biasB = b_ih[rowB] + b_hh[rowB];

    float h = 0.0f, c = 0.0f;

    __syncthreads();

    for (int t = 0; t < LSTM_T; ++t) {
        const float xv = sx[t];   // wave-uniform LDS broadcast
        // gates = xp + h @ W_hh^T   (4 accumulator chains for ILP)
        float gA0 = wihA * xv + biasA;
        float gB0 = wihB * xv + biasB;
        float gA1 = 0.0f, gB1 = 0.0f;
        #pragma unroll
        for (int k = 0; k < LSTM_H; k += 2) {
            const float h0 = rl(h, k);
            const float h1 = rl(h, k + 1);
            gA0 += wA[k]     * h0;
            gB0 += wB[k]     * h0;
            gA1 += wA[k + 1] * h1;
            gB1 += wB[k + 1] * h1;
        }
        const float gateA = gA0 + gA1;
        const float gateB = gB0 + gB1;

        float vA, vB;
        if (wv == 0) {                       // wave-uniform branch
            vA = fast_sigmoid(gateA);        // i
            vB = fast_sigmoid(gateB);        // f
        } else {
            vA = fast_tanh(gateA);           // g
            vB = fast_sigmoid(gateB);        // o
        }

        const int p = t & 1;
        ex[p][wv * 2 + 0][lane] = vA;
        ex[p][wv * 2 + 1][lane] = vB;
        __syncthreads();                     // single barrier per step (dbuf)

        float iv, fv, gv, ov;
        if (wv == 0) {
            iv = vA;               fv = vB;
            gv = ex[p][2][lane];   ov = ex[p][3][lane];
        } else {
            iv = ex[p][0][lane];   fv = ex[p][1][lane];
            gv = vA;               ov = vB;
        }
        // both waves update c,h redundantly -> h replicated, no 2nd barrier
        c = fv * c + iv * gv;
        h = ov * fast_tanh(c);
    }

    // ---- final linear [3,H] + log_softmax, wave 0 only ----
    if (wv == 0) {
        float p0 = h * W_lin[0 * LSTM_H + lane];
        float p1 = h * W_lin[1 * LSTM_H + lane];
        float p2 = h * W_lin[2 * LSTM_H + lane];
        #pragma unroll
        for (int off = 32; off > 0; off >>= 1) {
            p0 += __shfl_down(p0, off);
            p1 += __shfl_down(p1, off);
            p2 += __shfl_down(p2, off);
        }
        if (lane == 0) {
            const float l0 = p0 + b_lin[0];
            const float l1 = p1 + b_lin[1];
            const float l2 = p2 + b_lin[2];
            const float m  = fmaxf(l0, fmaxf(l1, l2));
            const float s  = __expf(l0 - m) + __expf(l1 - m) + __expf(l2 - m);
            const float ls = logf(s);
            out[b * 3 + 0] = l0 - m - ls;
            out[b * 3 + 1] = l1 - m - ls;
            out[b * 3 + 2] = l2 - m - ls;
        }
    }
}

extern "C" void kernel_launch(void* const* d_in, const int* in_sizes, int n_in,
                              void* d_out, int out_size, void* d_ws, size_t ws_size,
                              hipStream_t stream) {
    const float* x     = (const float*)d_in[0];
    const float* W_ih  = (const float*)d_in[1];
    const float* W_hh  = (const float*)d_in[2];
    const float* b_ih  = (const float*)d_in[3];
    const float* b_hh  = (const float*)d_in[4];
    const float* W_lin = (const float*)d_in[5];
    const float* b_lin = (const float*)d_in[6];
    float* out = (float*)d_out;

    const int B = in_sizes[0] / LSTM_T;   // 2048
    lstm_cls_kernel<<<B, 128, 0, stream>>>(x, W_ih, W_hh, b_ih, b_hh,
                                           W_lin, b_lin, out);
}